// Round 4
// baseline (1577.988 us; speedup 1.0000x reference)
//
#include <hip/hip_runtime.h>
#include <hip/hip_bf16.h>

typedef __bf16 bf16;
typedef __attribute__((ext_vector_type(8))) __bf16 bf16x8;
typedef __attribute__((ext_vector_type(4))) __bf16 bf16x4;
typedef __attribute__((ext_vector_type(4))) float f32x4;

#define E_TOTAL   1000000
#define N_TILES   15625          // E_TOTAL / 64
#define PGRID     768            // persistent grid: 3 blocks/CU x 256 CU
#define NODE_DIM  128
#define EDGE_DIM  64

// LDS strides (bf16 elems): multiples of 8 (16B rows), ≡4 dwords mod 32 →
// 2-way bank aliasing only (free on gfx950, m136).
#define SA_STRIDE  328   // 320 + 8
#define SH1_STRIDE 264   // 256 + 8
#define SH2_STRIDE 136   // 128 + 8
#define SH3_STRIDE 72    // 64 + 8

// Phase-aliased LDS plan (sA dead after GEMM1 MFMAs; sH1 dead after GEMM2):
//   phase A: sA  @0      [64][328] = 41984 B
//   phase B: sH1 @0      [64][264] = 33792 B   (aliases sA; extra barrier)
//            sH2 @33792  [64][136] = 17408 B   (end 51200)
//            sH3 @0      [64][72]  =  9216 B   (aliases dead sH1)
// peak = 51200 B -> 3 blocks/CU.
#define SMEM_BYTES 51200
#define SH2_OFF    33792

// ws layout, BIG mode (ws_size >= WS_NEED):
//   [0, 25600000)  xbf bf16[100000*128]
//   then W1f (163840 B), W2f (65536), W3f (16384), cano fp32[516] (2064), flags (16)
// cano: [0,256) b1 | [256,384) b2 | [384,448) b3 | 448 b4 | 449..451 pad |
//       [452,516) W4
// SMALL mode: same minus xbf, weights at offset 0.
#define WS_XBF_BYTES 25600000
#define WB_W2F  163840
#define WB_W3F  (163840 + 65536)
#define WB_CANO (163840 + 65536 + 16384)
#define WB_FLAG (163840 + 65536 + 16384 + 2064)
#define WB_END  (163840 + 65536 + 16384 + 2064 + 16)
#define WS_NEED (WS_XBF_BYTES + WB_END)

// ---------------------------------------------------------------------------
// Dtype sniffing (fp32 proven empirically; keep as runtime guard).
// ---------------------------------------------------------------------------
__device__ inline int plausible16(const unsigned short* h) {
    int c = 0;
    for (int i = 0; i < 64; ++i) {
        int e = (h[i] >> 7) & 0xFF;
        if (e >= 90 && e <= 151) ++c;
    }
    return c;
}

__global__ void sniff(const void* x, const void* ei, const void* ef,
                      const void* W1, int* flags) {
    if (threadIdx.x == 0 && blockIdx.x == 0) {
        flags[0] = (plausible16((const unsigned short*)x)  < 52) ? 1 : 0;
        flags[1] = (plausible16((const unsigned short*)ef) < 52) ? 1 : 0;
        flags[2] = (plausible16((const unsigned short*)W1) < 52) ? 1 : 0;
        const int* w = (const int*)ei;
        int oz = 0, lo_ok = 1;
        for (int i = 1; i < 32; i += 2) if (w[i] == 0) ++oz;
        for (int i = 0; i < 32; i += 2) if ((unsigned)w[i] >= 100000u) lo_ok = 0;
        flags[3] = (oz == 16 && lo_ok) ? 1 : 0;
    }
}

__device__ inline float loadF(const void* p, int isf, int i) {
    return isf ? ((const float*)p)[i] : (float)((const bf16*)p)[i];
}

// ---------------------------------------------------------------------------
// Weights -> frag-major. The (lane,reg)->(k,feature) mapping is identical for
// the MFMA A-frag (A[m=l16][k=quad*8+jj]) and B-frag (B[k=quad*8+jj][n=l16]),
// so this layout serves the TRANSPOSED chain (weights as A operand: lane holds
// W^T[feat = jt*16+l16][k = ks*32+quad*8+jj] = W[k][feat]) with no change.
// A wave's frag load is one coalesced 1KB stream.
// ---------------------------------------------------------------------------
__global__ void canonicalize(const void* W1, const void* W2, const void* W3,
                             const void* b1, const void* b2, const void* b3,
                             const void* W4, const void* b4,
                             bf16* W1f, bf16* W2f, bf16* W3f,
                             float* cano, const int* flags) {
    int isf = flags[2];
    int o = blockIdx.x * 256 + threadIdx.x;
    if (o < 81920) {                        // W1 [320][256] -> frag-major
        int jj = o & 7, lane = (o >> 3) & 63, t2 = o >> 9;
        int ks = t2 % 10, jt = t2 / 10;
        int k = ks * 32 + (lane >> 4) * 8 + jj;
        int n = jt * 16 + (lane & 15);
        W1f[o] = (bf16)loadF(W1, isf, k * 256 + n);
    } else if (o < 114688) {                // W2 [256][128]
        int o2 = o - 81920;
        int jj = o2 & 7, lane = (o2 >> 3) & 63, t2 = o2 >> 9;
        int ks = t2 & 7, jt = t2 >> 3;
        int k = ks * 32 + (lane >> 4) * 8 + jj;
        int n = jt * 16 + (lane & 15);
        W2f[o2] = (bf16)loadF(W2, isf, k * 128 + n);
    } else if (o < 122880) {                // W3 [128][64]
        int o3 = o - 114688;
        int jj = o3 & 7, lane = (o3 >> 3) & 63, t2 = o3 >> 9;
        int ks = t2 & 3, jt = t2 >> 2;
        int k = ks * 32 + (lane >> 4) * 8 + jj;
        int n = jt * 16 + (lane & 15);
        W3f[o3] = (bf16)loadF(W3, isf, k * 64 + n);
    } else if (o < 123396) {                // cano fp32: b1 b2 b3 b4 pad W4
        int j = o - 122880;
        float v;
        if (j < 256)       v = loadF(b1, isf, j);
        else if (j < 384)  v = loadF(b2, isf, j - 256);
        else if (j < 448)  v = loadF(b3, isf, j - 384);
        else if (j == 448) v = loadF(b4, isf, 0);
        else if (j < 452)  v = 0.f;                    // pad for W4 alignment
        else               v = loadF(W4, isf, j - 452);
        cano[j] = v;
    }
}

// x -> bf16 (halves gather bytes; x_bf16 = 25.6 MB ≈ L2-aggregate scale).
__global__ void convert_x(const void* x, bf16* xbf, const int* flags) {
    int i = (blockIdx.x * 256 + threadIdx.x) * 4;   // 12500 blocks covers 12.8M
    if (flags[0]) {
        const float* f = (const float*)x + i;
        bf16 v0 = (bf16)f[0], v1 = (bf16)f[1], v2 = (bf16)f[2], v3 = (bf16)f[3];
        xbf[i] = v0; xbf[i + 1] = v1; xbf[i + 2] = v2; xbf[i + 3] = v3;
    } else {
        *(unsigned long long*)(xbf + i) = *(const unsigned long long*)((const bf16*)x + i);
    }
}

// ---------------------------------------------------------------------------
// PERSISTENT fused MLP (BIG mode: x pre-converted to bf16). 768 blocks
// (3/CU) grid-stride over 15625 tiles of 64 edges. Cross-tile register
// prefetch: while tile t computes, tile t+PGRID's edge indices are loaded
// (hidden under GEMM1) and its x-gathers/ef loads are issued after GEMM1's
// epilogue (acc1 regs dead), staying in flight across GEMM2/G3/stage4 and
// consumed by the sA write at the next loop head. Removes the two-level
// gather latency chain (ei -> x, ~600-1300 cy) from the critical path.
// Compute phases are bit-identical to the R2 kernel (same math order).
//   MFMA 16x16x32 bf16: A: lane holds A[m=l16][k=quad*8+j]
//                       B: lane holds B[k=quad*8+j][n=l16]
//                       C/D: reg r = D[row=quad*4+r][col=l16]
// ---------------------------------------------------------------------------
__global__ __launch_bounds__(256, 3) void fused_mlp_persist(
    const bf16* __restrict__ xs, const int* __restrict__ ei, const void* __restrict__ ef,
    const bf16* __restrict__ W1f, const bf16* __restrict__ W2f,
    const bf16* __restrict__ W3f,
    const float* __restrict__ cano, const int* __restrict__ flags,
    float* __restrict__ out)
{
    __shared__ __align__(16) char smem[SMEM_BYTES];
    bf16* sA  = (bf16*)smem;                 // phase A: [64][328]
    bf16* sH1 = (bf16*)smem;                 // phase B: [64][264] aliases dead sA
    bf16* sH2 = (bf16*)(smem + SH2_OFF);     // [64][136]
    bf16* sH3 = (bf16*)smem;                 // [64][72] aliases dead sH1

    const int tid  = threadIdx.x;
    const int wave = tid >> 6;
    const int lane = tid & 63;
    const int quad = lane >> 4;
    const int l16  = lane & 15;

    const int isfe = flags[1];
    const int is64 = flags[3];

    // staging roles (fixed per thread)
    const int xrow0 = tid >> 5;          // x rows i*8 + xrow0
    const int xseg  = tid & 31;          // k = xseg*8 (0..255)
    const int which = xseg >> 4;         // 0: v-endpoint, 1: u-endpoint
    const int xk    = (xseg & 15) << 3;  // k within node row
    const int eseg  = tid & 7;           // ef: rows er0, er1, k=256+eseg*8
    const int er0   = tid >> 3;
    const int er1   = er0 + 32;

    int t = blockIdx.x;

    // prefetch state (consumed at next loop head)
    int    nidx[8];
    bf16x8 xb[8];
    float  efa[8], efb[8];
    bf16x8 efv0, efv1;

    // ---- prologue: synchronous prefetch of tile t ----
    {
        const int e0 = t * 64;
#pragma unroll
        for (int i = 0; i < 8; ++i) {
            size_t pos = which ? (size_t)(E_TOTAL + e0 + i * 8 + xrow0)
                               : (size_t)(e0 + i * 8 + xrow0);
            nidx[i] = is64 ? ei[2 * pos] : ei[pos];
        }
#pragma unroll
        for (int i = 0; i < 8; ++i)
            xb[i] = *(const bf16x8*)(xs + (size_t)nidx[i] * NODE_DIM + xk);
        if (isfe) {
            const float* f0 = (const float*)ef + (size_t)(e0 + er0) * EDGE_DIM + eseg * 8;
            const float* f1 = (const float*)ef + (size_t)(e0 + er1) * EDGE_DIM + eseg * 8;
#pragma unroll
            for (int j = 0; j < 8; ++j) { efa[j] = f0[j]; efb[j] = f1[j]; }
        } else {
            const bf16* eb = (const bf16*)ef;
            efv0 = *(const bf16x8*)(eb + (size_t)(t * 64 + er0) * EDGE_DIM + eseg * 8);
            efv1 = *(const bf16x8*)(eb + (size_t)(t * 64 + er1) * EDGE_DIM + eseg * 8);
        }
    }

    while (true) {
        const int e0 = t * 64;

        // ---- write prefetched tile -> sA (waitcnt auto-inserted) ----
#pragma unroll
        for (int i = 0; i < 8; ++i)
            *(bf16x8*)&sA[(i * 8 + xrow0) * SA_STRIDE + xseg * 8] = xb[i];
        {
            const int kst = 256 + eseg * 8;
            if (isfe) {
                bf16x8 v0, v1;
#pragma unroll
                for (int j = 0; j < 8; ++j) { v0[j] = (bf16)efa[j]; v1[j] = (bf16)efb[j]; }
                *(bf16x8*)&sA[er0 * SA_STRIDE + kst] = v0;
                *(bf16x8*)&sA[er1 * SA_STRIDE + kst] = v1;
            } else {
                *(bf16x8*)&sA[er0 * SA_STRIDE + kst] = efv0;
                *(bf16x8*)&sA[er1 * SA_STRIDE + kst] = efv1;
            }
        }
        __syncthreads();

        const int  tn   = t + PGRID;
        const bool more = tn < N_TILES;

        // ---- prefetch next tile's edge indices (latency hides under G1) ----
        if (more) {
            const int en = tn * 64;
#pragma unroll
            for (int i = 0; i < 8; ++i) {
                size_t pos = which ? (size_t)(E_TOTAL + en + i * 8 + xrow0)
                                   : (size_t)(en + i * 8 + xrow0);
                nidx[i] = is64 ? ei[2 * pos] : ei[pos];
            }
        }

        // ------- GEMM1T: W1^T[256,320] x A^T[320,64] -> sH1 -------
        f32x4 acc1[4][4];
#pragma unroll
        for (int p = 0; p < 4; ++p)
#pragma unroll
            for (int q = 0; q < 4; ++q)
                acc1[p][q] = (f32x4){0.f, 0.f, 0.f, 0.f};

        const bf16* w1base = W1f + (size_t)wave * (40 * 512) + lane * 8;
#pragma unroll
        for (int ks = 0; ks < 10; ++ks) {
            bf16x8 w[4], e[4];
#pragma unroll
            for (int p = 0; p < 4; ++p)
                w[p] = *(const bf16x8*)(w1base + (p * 10 + ks) * 512);
#pragma unroll
            for (int q = 0; q < 4; ++q)
                e[q] = *(const bf16x8*)&sA[(16 * q + l16) * SA_STRIDE + ks * 32 + quad * 8];
#pragma unroll
            for (int p = 0; p < 4; ++p)
#pragma unroll
                for (int q = 0; q < 4; ++q)
                    acc1[p][q] = __builtin_amdgcn_mfma_f32_16x16x32_bf16(
                        w[p], e[q], acc1[p][q], 0, 0, 0);
        }
        // sA fully consumed by ALL waves before sH1 (same bytes) is written.
        __syncthreads();
        {   // bias + relu -> sH1[edge][feat], packed b64
#pragma unroll
            for (int p = 0; p < 4; ++p) {
                f32x4 bias = *(const f32x4*)&cano[64 * wave + 16 * p + 4 * quad];
#pragma unroll
                for (int q = 0; q < 4; ++q) {
                    bf16x4 pv;
#pragma unroll
                    for (int r = 0; r < 4; ++r)
                        pv[r] = (bf16)fmaxf(acc1[p][q][r] + bias[r], 0.f);
                    *(bf16x4*)&sH1[(16 * q + l16) * SH1_STRIDE + 64 * wave + 16 * p + 4 * quad] = pv;
                }
            }
        }
        __syncthreads();

        // ---- issue next tile's gathers NOW (acc1 dead; in flight across
        //      G2+G3+stage4, consumed at next loop head) ----
        if (more) {
#pragma unroll
            for (int i = 0; i < 8; ++i)
                xb[i] = *(const bf16x8*)(xs + (size_t)nidx[i] * NODE_DIM + xk);
            const int en = tn * 64;
            if (isfe) {
                const float* f0 = (const float*)ef + (size_t)(en + er0) * EDGE_DIM + eseg * 8;
                const float* f1 = (const float*)ef + (size_t)(en + er1) * EDGE_DIM + eseg * 8;
#pragma unroll
                for (int j = 0; j < 8; ++j) { efa[j] = f0[j]; efb[j] = f1[j]; }
            } else {
                const bf16* eb = (const bf16*)ef;
                efv0 = *(const bf16x8*)(eb + (size_t)(en + er0) * EDGE_DIM + eseg * 8);
                efv1 = *(const bf16x8*)(eb + (size_t)(en + er1) * EDGE_DIM + eseg * 8);
            }
        }

        // ------- GEMM2T: W2^T[128,256] x H1^T[256,64] -> sH2 -------
        f32x4 acc2[2][4];
#pragma unroll
        for (int p = 0; p < 2; ++p)
#pragma unroll
            for (int q = 0; q < 4; ++q)
                acc2[p][q] = (f32x4){0.f, 0.f, 0.f, 0.f};
        const bf16* w2base = W2f + (size_t)wave * (16 * 512) + lane * 8;
#pragma unroll
        for (int ks = 0; ks < 8; ++ks) {
            bf16x8 w[2], e[4];
#pragma unroll
            for (int p = 0; p < 2; ++p)
                w[p] = *(const bf16x8*)(w2base + (p * 8 + ks) * 512);
#pragma unroll
            for (int q = 0; q < 4; ++q)
                e[q] = *(const bf16x8*)&sH1[(16 * q + l16) * SH1_STRIDE + ks * 32 + quad * 8];
#pragma unroll
            for (int p = 0; p < 2; ++p)
#pragma unroll
                for (int q = 0; q < 4; ++q)
                    acc2[p][q] = __builtin_amdgcn_mfma_f32_16x16x32_bf16(
                        w[p], e[q], acc2[p][q], 0, 0, 0);
        }
        {   // sH2 is a fresh region — no extra barrier before writing.
#pragma unroll
            for (int p = 0; p < 2; ++p) {
                f32x4 bias = *(const f32x4*)&cano[256 + 32 * wave + 16 * p + 4 * quad];
#pragma unroll
                for (int q = 0; q < 4; ++q) {
                    bf16x4 pv;
#pragma unroll
                    for (int r = 0; r < 4; ++r)
                        pv[r] = (bf16)fmaxf(acc2[p][q][r] + bias[r], 0.f);
                    *(bf16x4*)&sH2[(16 * q + l16) * SH2_STRIDE + 32 * wave + 16 * p + 4 * quad] = pv;
                }
            }
        }
        __syncthreads();

        // ------- GEMM3T: W3^T[64,128] x H2^T[128,64] -> sH3 -------
        f32x4 acc3[4];
#pragma unroll
        for (int q = 0; q < 4; ++q) acc3[q] = (f32x4){0.f, 0.f, 0.f, 0.f};
        const bf16* w3base = W3f + (size_t)wave * (4 * 512) + lane * 8;
#pragma unroll
        for (int ks = 0; ks < 4; ++ks) {
            bf16x8 w = *(const bf16x8*)(w3base + ks * 512);
#pragma unroll
            for (int q = 0; q < 4; ++q) {
                bf16x8 e = *(const bf16x8*)&sH2[(16 * q + l16) * SH2_STRIDE + ks * 32 + quad * 8];
                acc3[q] = __builtin_amdgcn_mfma_f32_16x16x32_bf16(w, e, acc3[q], 0, 0, 0);
            }
        }
        {   // sH3 aliases sH1; last sH1 reads fenced by the post-G2 barrier.
            f32x4 bias = *(const f32x4*)&cano[384 + 16 * wave + 4 * quad];
#pragma unroll
            for (int q = 0; q < 4; ++q) {
                bf16x4 pv;
#pragma unroll
                for (int r = 0; r < 4; ++r)
                    pv[r] = (bf16)fmaxf(acc3[q][r] + bias[r], 0.f);
                *(bf16x4*)&sH3[(16 * q + l16) * SH3_STRIDE + 16 * wave + 4 * quad] = pv;
            }
        }
        __syncthreads();

        // ---- Stage 4: h3[64] · W4 + b4 -> out ----
        {
            int edge = tid >> 2;
            int part = tid & 3;
            int k0 = part * 16;
            const bf16* h = &sH3[edge * SH3_STRIDE + k0];
            bf16x8 h0 = *(const bf16x8*)h;
            bf16x8 h1 = *(const bf16x8*)(h + 8);
            float s = 0.f;
#pragma unroll
            for (int k = 0; k < 8; ++k) s += (float)h0[k] * cano[452 + k0 + k];
#pragma unroll
            for (int k = 0; k < 8; ++k) s += (float)h1[k] * cano[452 + k0 + 8 + k];
            s += __shfl_xor(s, 1);
            s += __shfl_xor(s, 2);
            if (part == 0) out[e0 + edge] = s + cano[448];
        }

        if (!more) break;
        __syncthreads();   // sH3 (@0) fully read before next tile's sA write
        t = tn;
    }
}

// ---------------------------------------------------------------------------
// SMALL-mode fallback (runtime x dtype, non-persistent) — R2 structure.
// ---------------------------------------------------------------------------
__global__ __launch_bounds__(256, 3) void fused_mlp(
    const void* __restrict__ xs, const int* __restrict__ ei, const void* __restrict__ ef,
    const bf16* __restrict__ W1f, const bf16* __restrict__ W2f,
    const bf16* __restrict__ W3f,
    const float* __restrict__ cano, const int* __restrict__ flags,
    int xmode_host, float* __restrict__ out)
{
    __shared__ __align__(16) char smem[SMEM_BYTES];
    bf16* sA  = (bf16*)smem;
    bf16* sH1 = (bf16*)smem;
    bf16* sH2 = (bf16*)(smem + SH2_OFF);
    bf16* sH3 = (bf16*)smem;

    const int tid  = threadIdx.x;
    const int wave = tid >> 6;
    const int lane = tid & 63;
    const int quad = lane >> 4;
    const int l16  = lane & 15;
    const int e0   = blockIdx.x * 64;

    const int isfe = flags[1];
    const int is64 = flags[3];
    const int xm   = (xmode_host < 0) ? flags[0] : xmode_host;

    {
        const int xrow0 = tid >> 5;
        const int xseg  = tid & 31;
        const int which = xseg >> 4;
        const int xk    = (xseg & 15) << 3;
        if (xm == 0) {
            const bf16* xsb = (const bf16*)xs;
            bf16x8 xb[8];
#pragma unroll
            for (int i = 0; i < 8; ++i) {
                int row = i * 8 + xrow0;
                size_t pos = which ? (size_t)(E_TOTAL + e0 + row) : (size_t)(e0 + row);
                int node = is64 ? ei[2 * pos] : ei[pos];
                xb[i] = *(const bf16x8*)(xsb + (size_t)node * NODE_DIM + xk);
            }
#pragma unroll
            for (int i = 0; i < 8; ++i)
                *(bf16x8*)&sA[(i * 8 + xrow0) * SA_STRIDE + xseg * 8] = xb[i];
        } else {
            const float* xsf = (const float*)xs;
            float xf[8][8];
#pragma unroll
            for (int i = 0; i < 8; ++i) {
                int row = i * 8 + xrow0;
                size_t pos = which ? (size_t)(E_TOTAL + e0 + row) : (size_t)(e0 + row);
                int node = is64 ? ei[2 * pos] : ei[pos];
                const float* f = xsf + (size_t)node * NODE_DIM + xk;
#pragma unroll
                for (int j = 0; j < 8; ++j) xf[i][j] = f[j];
            }
#pragma unroll
            for (int i = 0; i < 8; ++i) {
                bf16x8 v;
#pragma unroll
                for (int j = 0; j < 8; ++j) v[j] = (bf16)xf[i][j];
                *(bf16x8*)&sA[(i * 8 + xrow0) * SA_STRIDE + xseg * 8] = v;
            }
        }
        int seg = tid & 7, r0 = tid >> 3, r1 = r0 + 32;
        int kst = 256 + seg * 8;
        if (isfe) {
            const float* f0 = (const float*)ef + (size_t)(e0 + r0) * EDGE_DIM + seg * 8;
            const float* f1 = (const float*)ef + (size_t)(e0 + r1) * EDGE_DIM + seg * 8;
            float a0[8], a1[8];
#pragma unroll
            for (int j = 0; j < 8; ++j) { a0[j] = f0[j]; a1[j] = f1[j]; }
            bf16x8 v0, v1;
#pragma unroll
            for (int j = 0; j < 8; ++j) { v0[j] = (bf16)a0[j]; v1[j] = (bf16)a1[j]; }
            *(bf16x8*)&sA[r0 * SA_STRIDE + kst] = v0;
            *(bf16x8*)&sA[r1 * SA_STRIDE + kst] = v1;
        } else {
            const bf16* eb = (const bf16*)ef;
            bf16x8 v0 = *(const bf16x8*)(eb + (size_t)(e0 + r0) * EDGE_DIM + seg * 8);
            bf16x8 v1 = *(const bf16x8*)(eb + (size_t)(e0 + r1) * EDGE_DIM + seg * 8);
            *(bf16x8*)&sA[r0 * SA_STRIDE + kst] = v0;
            *(bf16x8*)&sA[r1 * SA_STRIDE + kst] = v1;
        }
    }
    __syncthreads();

    f32x4 acc1[4][4];
#pragma unroll
    for (int p = 0; p < 4; ++p)
#pragma unroll
        for (int q = 0; q < 4; ++q)
            acc1[p][q] = (f32x4){0.f, 0.f, 0.f, 0.f};

    const bf16* w1base = W1f + (size_t)wave * (40 * 512) + lane * 8;
#pragma unroll
    for (int ks = 0; ks < 10; ++ks) {
        bf16x8 w[4], e[4];
#pragma unroll
        for (int p = 0; p < 4; ++p)
            w[p] = *(const bf16x8*)(w1base + (p * 10 + ks) * 512);
#pragma unroll
        for (int q = 0; q < 4; ++q)
            e[q] = *(const bf16x8*)&sA[(16 * q + l16) * SA_STRIDE + ks * 32 + quad * 8];
#pragma unroll
        for (int p = 0; p < 4; ++p)
#pragma unroll
            for (int q = 0; q < 4; ++q)
                acc1[p][q] = __builtin_amdgcn_mfma_f32_16x16x32_bf16(
                    w[p], e[q], acc1[p][q], 0, 0, 0);
    }
    __syncthreads();
    {
#pragma unroll
        for (int p = 0; p < 4; ++p) {
            f32x4 bias = *(const f32x4*)&cano[64 * wave + 16 * p + 4 * quad];
#pragma unroll
            for (int q = 0; q < 4; ++q) {
                bf16x4 pv;
#pragma unroll
                for (int r = 0; r < 4; ++r)
                    pv[r] = (bf16)fmaxf(acc1[p][q][r] + bias[r], 0.f);
                *(bf16x4*)&sH1[(16 * q + l16) * SH1_STRIDE + 64 * wave + 16 * p + 4 * quad] = pv;
            }
        }
    }
    __syncthreads();

    f32x4 acc2[2][4];
#pragma unroll
    for (int p = 0; p < 2; ++p)
#pragma unroll
        for (int q = 0; q < 4; ++q)
            acc2[p][q] = (f32x4){0.f, 0.f, 0.f, 0.f};
    const bf16* w2base = W2f + (size_t)wave * (16 * 512) + lane * 8;
#pragma unroll
    for (int ks = 0; ks < 8; ++ks) {
        bf16x8 w[2], e[4];
#pragma unroll
        for (int p = 0; p < 2; ++p)
            w[p] = *(const bf16x8*)(w2base + (p * 8 + ks) * 512);
#pragma unroll
        for (int q = 0; q < 4; ++q)
            e[q] = *(const bf16x8*)&sH1[(16 * q + l16) * SH1_STRIDE + ks * 32 + quad * 8];
#pragma unroll
        for (int p = 0; p < 2; ++p)
#pragma unroll
            for (int q = 0; q < 4; ++q)
                acc2[p][q] = __builtin_amdgcn_mfma_f32_16x16x32_bf16(
                    w[p], e[q], acc2[p][q], 0, 0, 0);
    }
    {
#pragma unroll
        for (int p = 0; p < 2; ++p) {
            f32x4 bias = *(const f32x4*)&cano[256 + 32 * wave + 16 * p + 4 * quad];
#pragma unroll
            for (int q = 0; q < 4; ++q) {
                bf16x4 pv;
#pragma unroll
                for (int r = 0; r < 4; ++r)
                    pv[r] = (bf16)fmaxf(acc2[p][q][r] + bias[r], 0.f);
                *(bf16x4*)&sH2[(16 * q + l16) * SH2_STRIDE + 32 * wave + 16 * p + 4 * quad] = pv;
            }
        }
    }
    __syncthreads();

    f32x4 acc3[4];
#pragma unroll
    for (int q = 0; q < 4; ++q) acc3[q] = (f32x4){0.f, 0.f, 0.f, 0.f};
    const bf16* w3base = W3f + (size_t)wave * (4 * 512) + lane * 8;
#pragma unroll
    for (int ks = 0; ks < 4; ++ks) {
        bf16x8 w = *(const bf16x8*)(w3base + ks * 512);
#pragma unroll
        for (int q = 0; q < 4; ++q) {
            bf16x8 e = *(const bf16x8*)&sH2[(16 * q + l16) * SH2_STRIDE + ks * 32 + quad * 8];
            acc3[q] = __builtin_amdgcn_mfma_f32_16x16x32_bf16(w, e, acc3[q], 0, 0, 0);
        }
    }
    {
        f32x4 bias = *(const f32x4*)&cano[384 + 16 * wave + 4 * quad];
#pragma unroll
        for (int q = 0; q < 4; ++q) {
            bf16x4 pv;
#pragma unroll
            for (int r = 0; r < 4; ++r)
                pv[r] = (bf16)fmaxf(acc3[q][r] + bias[r], 0.f);
            *(bf16x4*)&sH3[(16 * q + l16) * SH3_STRIDE + 16 * wave + 4 * quad] = pv;
        }
    }
    __syncthreads();

    {
        int edge = tid >> 2;
        int part = tid & 3;
        int k0 = part * 16;
        const bf16* h = &sH3[edge * SH3_STRIDE + k0];
        bf16x8 h0 = *(const bf16x8*)h;
        bf16x8 h1 = *(const bf16x8*)(h + 8);
        float s = 0.f;
#pragma unroll
        for (int k = 0; k < 8; ++k) s += (float)h0[k] * cano[452 + k0 + k];
#pragma unroll
        for (int k = 0; k < 8; ++k) s += (float)h1[k] * cano[452 + k0 + 8 + k];
        s += __shfl_xor(s, 1);
        s += __shfl_xor(s, 2);
        if (part == 0) out[e0 + edge] = s + cano[448];
    }
}

extern "C" void kernel_launch(void* const* d_in, const int* in_sizes, int n_in,
                              void* d_out, int out_size, void* d_ws, size_t ws_size,
                              hipStream_t stream) {
    const void* x  = d_in[0];
    const int*  ei = (const int*)d_in[1];
    const void* ef = d_in[2];
    const void* W1 = d_in[4];
    const void* b1 = d_in[5];
    const void* W2 = d_in[6];
    const void* b2 = d_in[7];
    const void* W3 = d_in[8];
    const void* b3 = d_in[9];
    const void* W4 = d_in[10];
    const void* b4 = d_in[11];
    float* out = (float*)d_out;

    char* ws = (char*)d_ws;
    const bool big = ws_size >= (size_t)WS_NEED;   // ws_size constant per session
    bf16* xbf   = (bf16*)ws;                       // BIG mode only
    char* wbase = big ? (ws + WS_XBF_BYTES) : ws;
    bf16*  W1f   = (bf16*)wbase;
    bf16*  W2f   = (bf16*)(wbase + WB_W2F);
    bf16*  W3f   = (bf16*)(wbase + WB_W3F);
    float* cano  = (float*)(wbase + WB_CANO);
    int*   flags = (int*)(wbase + WB_FLAG);

    sniff<<<1, 64, 0, stream>>>(x, ei, ef, W1, flags);
    canonicalize<<<483, 256, 0, stream>>>(W1, W2, W3, b1, b2, b3, W4, b4,
                                          W1f, W2f, W3f, cano, flags);
    if (big) {
        convert_x<<<12500, 256, 0, stream>>>(x, xbf, flags);
        fused_mlp_persist<<<PGRID, 256, 0, stream>>>(
            xbf, ei, ef, W1f, W2f, W3f, cano, flags, out);
    } else {
        fused_mlp<<<E_TOTAL / 64, 256, 0, stream>>>(
            x, ei, ef, W1f, W2f, W3f, cano, flags, -1, out);
    }
}

// Round 5
// 644.040 us; speedup vs baseline: 2.4501x; 2.4501x over previous
//
#include <hip/hip_runtime.h>
#include <hip/hip_bf16.h>

typedef __bf16 bf16;
typedef __attribute__((ext_vector_type(8))) __bf16 bf16x8;
typedef __attribute__((ext_vector_type(4))) __bf16 bf16x4;
typedef __attribute__((ext_vector_type(4))) float f32x4;

#define E_TOTAL   1000000
#define NODE_DIM  128
#define EDGE_DIM  64

// LDS strides (bf16 elems): multiples of 8 (16B rows), ≡4 dwords mod 32 →
// 2-way bank aliasing only (free on gfx950, m136).
#define SA_STRIDE  328   // 320 + 8
#define SH1_STRIDE 264   // 256 + 8
#define SH2_STRIDE 136   // 128 + 8
#define SH3_STRIDE 72    // 64 + 8

// LDS layout, barrier-minimized (R1 proved 2 blocks/CU ≡ 3 blocks/CU):
//   sA  @0      [64][328] = 41984 B   (phase A)
//   sH1 @41984  [64][264] = 33792 B   FRESH region -> G1 epilogue needs NO
//                                     barrier after G1 MFMAs (disjoint bytes)
//   sH2 @0      [64][136] = 17408 B   aliases dead sA (fenced by post-G1-epi
//                                     barrier: all sA reads precede it)
//   sH3 @17408  [64][72]  =  9216 B   aliases dead sA (disjoint from sH2)
// peak = 75776 B -> 2 blocks/CU. Barriers: 4 (was 5).
#define SMEM_BYTES 75776
#define SH1_OFF    41984
#define SH3_OFF    17408

// ws layout, BIG mode (ws_size >= WS_NEED):
//   [0, 25600000)  xbf bf16[100000*128]
//   then W1f (163840 B), W2f (65536), W3f (16384), cano fp32[516] (2064), flags (16)
// cano: [0,256) b1 | [256,384) b2 | [384,448) b3 | 448 b4 | 449..451 pad |
//       [452,516) W4  (452 ≡ 0 mod 4 -> f32x4-aligned loads in stage4)
// SMALL mode: same minus xbf, weights at offset 0.
#define WS_XBF_BYTES 25600000
#define WB_W2F  163840
#define WB_W3F  (163840 + 65536)
#define WB_CANO (163840 + 65536 + 16384)
#define WB_FLAG (163840 + 65536 + 16384 + 2064)
#define WB_END  (163840 + 65536 + 16384 + 2064 + 16)
#define WS_NEED (WS_XBF_BYTES + WB_END)

// ---------------------------------------------------------------------------
// Dtype sniffing (fp32 proven empirically; keep as runtime guard).
// ---------------------------------------------------------------------------
__device__ inline int plausible16(const unsigned short* h) {
    int c = 0;
    for (int i = 0; i < 64; ++i) {
        int e = (h[i] >> 7) & 0xFF;
        if (e >= 90 && e <= 151) ++c;
    }
    return c;
}

__global__ void sniff(const void* x, const void* ei, const void* ef,
                      const void* W1, int* flags) {
    if (threadIdx.x == 0 && blockIdx.x == 0) {
        flags[0] = (plausible16((const unsigned short*)x)  < 52) ? 1 : 0;
        flags[1] = (plausible16((const unsigned short*)ef) < 52) ? 1 : 0;
        flags[2] = (plausible16((const unsigned short*)W1) < 52) ? 1 : 0;
        const int* w = (const int*)ei;
        int oz = 0, lo_ok = 1;
        for (int i = 1; i < 32; i += 2) if (w[i] == 0) ++oz;
        for (int i = 0; i < 32; i += 2) if ((unsigned)w[i] >= 100000u) lo_ok = 0;
        flags[3] = (oz == 16 && lo_ok) ? 1 : 0;
    }
}

__device__ inline float loadF(const void* p, int isf, int i) {
    return isf ? ((const float*)p)[i] : (float)((const bf16*)p)[i];
}

// ---------------------------------------------------------------------------
// Weights -> frag-major. The (lane,reg)->(k,feature) mapping is identical for
// the MFMA A-frag (A[m=l16][k=quad*8+jj]) and B-frag (B[k=quad*8+jj][n=l16]),
// so this layout serves the TRANSPOSED chain (weights as A operand: lane holds
// W^T[feat = jt*16+l16][k = ks*32+quad*8+jj] = W[k][feat]) with no change.
// A wave's frag load is one coalesced 1KB stream.
// ---------------------------------------------------------------------------
__global__ void canonicalize(const void* W1, const void* W2, const void* W3,
                             const void* b1, const void* b2, const void* b3,
                             const void* W4, const void* b4,
                             bf16* W1f, bf16* W2f, bf16* W3f,
                             float* cano, const int* flags) {
    int isf = flags[2];
    int o = blockIdx.x * 256 + threadIdx.x;
    if (o < 81920) {                        // W1 [320][256] -> frag-major
        int jj = o & 7, lane = (o >> 3) & 63, t2 = o >> 9;
        int ks = t2 % 10, jt = t2 / 10;
        int k = ks * 32 + (lane >> 4) * 8 + jj;
        int n = jt * 16 + (lane & 15);
        W1f[o] = (bf16)loadF(W1, isf, k * 256 + n);
    } else if (o < 114688) {                // W2 [256][128]
        int o2 = o - 81920;
        int jj = o2 & 7, lane = (o2 >> 3) & 63, t2 = o2 >> 9;
        int ks = t2 & 7, jt = t2 >> 3;
        int k = ks * 32 + (lane >> 4) * 8 + jj;
        int n = jt * 16 + (lane & 15);
        W2f[o2] = (bf16)loadF(W2, isf, k * 128 + n);
    } else if (o < 122880) {                // W3 [128][64]
        int o3 = o - 114688;
        int jj = o3 & 7, lane = (o3 >> 3) & 63, t2 = o3 >> 9;
        int ks = t2 & 3, jt = t2 >> 2;
        int k = ks * 32 + (lane >> 4) * 8 + jj;
        int n = jt * 16 + (lane & 15);
        W3f[o3] = (bf16)loadF(W3, isf, k * 64 + n);
    } else if (o < 123396) {                // cano fp32: b1 b2 b3 b4 pad W4
        int j = o - 122880;
        float v;
        if (j < 256)       v = loadF(b1, isf, j);
        else if (j < 384)  v = loadF(b2, isf, j - 256);
        else if (j < 448)  v = loadF(b3, isf, j - 384);
        else if (j == 448) v = loadF(b4, isf, 0);
        else if (j < 452)  v = 0.f;                    // pad for W4 alignment
        else               v = loadF(W4, isf, j - 452);
        cano[j] = v;
    }
}

// x -> bf16 (halves gather bytes; x_bf16 = 25.6 MB ≈ L2-aggregate scale).
__global__ void convert_x(const void* x, bf16* xbf, const int* flags) {
    int i = (blockIdx.x * 256 + threadIdx.x) * 4;   // 12500 blocks covers 12.8M
    if (flags[0]) {
        const float* f = (const float*)x + i;
        bf16 v0 = (bf16)f[0], v1 = (bf16)f[1], v2 = (bf16)f[2], v3 = (bf16)f[3];
        xbf[i] = v0; xbf[i + 1] = v1; xbf[i + 2] = v2; xbf[i + 3] = v3;
    } else {
        *(unsigned long long*)(xbf + i) = *(const unsigned long long*)((const bf16*)x + i);
    }
}

// ---------------------------------------------------------------------------
// Fused MLP, TRANSPOSED chain: every layer computes H^T = W^T · A^T.
//   MFMA 16x16x32 bf16: A: lane holds A[m=l16][k=quad*8+j]
//                       B: lane holds B[k=quad*8+j][n=l16]
//                       C/D: reg r = D[row=quad*4+r][col=l16]
// Roles: m = output feature (wave owns a feature slab), n = edge, k = input
// feature. A operand = frag-major weights (global, coalesced). B operand =
// edge-major LDS tile (b128 reads). Epilogues pack bias+relu+cvt as b64.
// 4 barriers: sH1 is a fresh LDS region so no drain between G1 MFMA and its
// epilogue (R2 needed one because sH1 aliased sA).
// ---------------------------------------------------------------------------
__global__ __launch_bounds__(256, 2) void fused_mlp(
    const void* __restrict__ xs, const int* __restrict__ ei, const void* __restrict__ ef,
    const bf16* __restrict__ W1f, const bf16* __restrict__ W2f,
    const bf16* __restrict__ W3f,
    const float* __restrict__ cano, const int* __restrict__ flags,
    int xmode_host, float* __restrict__ out)
{
    __shared__ __align__(16) char smem[SMEM_BYTES];
    bf16* sA  = (bf16*)smem;                 // [64][328] phase A
    bf16* sH1 = (bf16*)(smem + SH1_OFF);     // [64][264] fresh region
    bf16* sH2 = (bf16*)smem;                 // [64][136] aliases dead sA
    bf16* sH3 = (bf16*)(smem + SH3_OFF);     // [64][72]  aliases dead sA

    const int tid  = threadIdx.x;
    const int wave = tid >> 6;
    const int lane = tid & 63;
    const int quad = lane >> 4;
    const int l16  = lane & 15;
    const int e0   = blockIdx.x * 64;

    const int isfe = flags[1];
    const int is64 = flags[3];
    const int xm   = (xmode_host < 0) ? flags[0] : xmode_host;

    // ---- stage full A-tile: x = 8 tasks/thread, ef = 2 tasks/thread ----
    {
        const int xrow0 = tid >> 5;          // rows i*8 + xrow0
        const int xseg  = tid & 31;          // k = xseg*8 (0..255)
        const int which = xseg >> 4;         // 0: v-endpoint, 1: u-endpoint
        const int xk    = (xseg & 15) << 3;  // k within node row
        if (xm == 0) {
            const bf16* xsb = (const bf16*)xs;
            bf16x8 xb[8];
#pragma unroll
            for (int i = 0; i < 8; ++i) {
                int row = i * 8 + xrow0;
                size_t pos = which ? (size_t)(E_TOTAL + e0 + row) : (size_t)(e0 + row);
                int node = is64 ? ei[2 * pos] : ei[pos];
                xb[i] = *(const bf16x8*)(xsb + (size_t)node * NODE_DIM + xk);
            }
#pragma unroll
            for (int i = 0; i < 8; ++i)
                *(bf16x8*)&sA[(i * 8 + xrow0) * SA_STRIDE + xseg * 8] = xb[i];
        } else {
            const float* xsf = (const float*)xs;
            float xf[8][8];
#pragma unroll
            for (int i = 0; i < 8; ++i) {
                int row = i * 8 + xrow0;
                size_t pos = which ? (size_t)(E_TOTAL + e0 + row) : (size_t)(e0 + row);
                int node = is64 ? ei[2 * pos] : ei[pos];
                const float* f = xsf + (size_t)node * NODE_DIM + xk;
#pragma unroll
                for (int j = 0; j < 8; ++j) xf[i][j] = f[j];
            }
#pragma unroll
            for (int i = 0; i < 8; ++i) {
                bf16x8 v;
#pragma unroll
                for (int j = 0; j < 8; ++j) v[j] = (bf16)xf[i][j];
                *(bf16x8*)&sA[(i * 8 + xrow0) * SA_STRIDE + xseg * 8] = v;
            }
        }
        // edge features: rows tid>>3 and +32, k = 256 + (tid&7)*8
        int seg = tid & 7, r0 = tid >> 3, r1 = r0 + 32;
        int kst = 256 + seg * 8;
        if (isfe) {
            const float* f0 = (const float*)ef + (size_t)(e0 + r0) * EDGE_DIM + seg * 8;
            const float* f1 = (const float*)ef + (size_t)(e0 + r1) * EDGE_DIM + seg * 8;
            float a0[8], a1[8];
#pragma unroll
            for (int j = 0; j < 8; ++j) { a0[j] = f0[j]; a1[j] = f1[j]; }
            bf16x8 v0, v1;
#pragma unroll
            for (int j = 0; j < 8; ++j) { v0[j] = (bf16)a0[j]; v1[j] = (bf16)a1[j]; }
            *(bf16x8*)&sA[r0 * SA_STRIDE + kst] = v0;
            *(bf16x8*)&sA[r1 * SA_STRIDE + kst] = v1;
        } else {
            const bf16* eb = (const bf16*)ef;
            bf16x8 v0 = *(const bf16x8*)(eb + (size_t)(e0 + r0) * EDGE_DIM + seg * 8);
            bf16x8 v1 = *(const bf16x8*)(eb + (size_t)(e0 + r1) * EDGE_DIM + seg * 8);
            *(bf16x8*)&sA[r0 * SA_STRIDE + kst] = v0;
            *(bf16x8*)&sA[r1 * SA_STRIDE + kst] = v1;
        }
    }
    __syncthreads();                                         // B1

    // ------- GEMM1T: W1^T[256,320] x A^T[320,64] -> sH1 (edge-major) -------
    // wave owns features 64*wave .. +63 (p=0..3); q spans 64 edges.
    f32x4 acc1[4][4];
#pragma unroll
    for (int p = 0; p < 4; ++p)
#pragma unroll
        for (int q = 0; q < 4; ++q)
            acc1[p][q] = (f32x4){0.f, 0.f, 0.f, 0.f};

    const bf16* w1base = W1f + (size_t)wave * (40 * 512) + lane * 8;
#pragma unroll
    for (int ks = 0; ks < 10; ++ks) {
        bf16x8 w[4], e[4];
#pragma unroll
        for (int p = 0; p < 4; ++p)
            w[p] = *(const bf16x8*)(w1base + (p * 10 + ks) * 512);
#pragma unroll
        for (int q = 0; q < 4; ++q)
            e[q] = *(const bf16x8*)&sA[(16 * q + l16) * SA_STRIDE + ks * 32 + quad * 8];
#pragma unroll
        for (int p = 0; p < 4; ++p)
#pragma unroll
            for (int q = 0; q < 4; ++q)
                acc1[p][q] = __builtin_amdgcn_mfma_f32_16x16x32_bf16(
                    w[p], e[q], acc1[p][q], 0, 0, 0);
    }
    {   // bias + relu -> sH1 (fresh region, disjoint from sA: NO barrier
        // needed between the MFMAs above and these writes).
#pragma unroll
        for (int p = 0; p < 4; ++p) {
            f32x4 bias = *(const f32x4*)&cano[64 * wave + 16 * p + 4 * quad];
#pragma unroll
            for (int q = 0; q < 4; ++q) {
                bf16x4 pv;
#pragma unroll
                for (int r = 0; r < 4; ++r)
                    pv[r] = (bf16)fmaxf(acc1[p][q][r] + bias[r], 0.f);
                *(bf16x4*)&sH1[(16 * q + l16) * SH1_STRIDE + 64 * wave + 16 * p + 4 * quad] = pv;
            }
        }
    }
    __syncthreads();                                         // B2

    // ------- GEMM2T: W2^T[128,256] x H1^T[256,64] -> sH2 -------
    f32x4 acc2[2][4];
#pragma unroll
    for (int p = 0; p < 2; ++p)
#pragma unroll
        for (int q = 0; q < 4; ++q)
            acc2[p][q] = (f32x4){0.f, 0.f, 0.f, 0.f};
    const bf16* w2base = W2f + (size_t)wave * (16 * 512) + lane * 8;
#pragma unroll
    for (int ks = 0; ks < 8; ++ks) {
        bf16x8 w[2], e[4];
#pragma unroll
        for (int p = 0; p < 2; ++p)
            w[p] = *(const bf16x8*)(w2base + (p * 8 + ks) * 512);
#pragma unroll
        for (int q = 0; q < 4; ++q)
            e[q] = *(const bf16x8*)&sH1[(16 * q + l16) * SH1_STRIDE + ks * 32 + quad * 8];
#pragma unroll
        for (int p = 0; p < 2; ++p)
#pragma unroll
            for (int q = 0; q < 4; ++q)
                acc2[p][q] = __builtin_amdgcn_mfma_f32_16x16x32_bf16(
                    w[p], e[q], acc2[p][q], 0, 0, 0);
    }
    {   // writes sH2 @0 (aliases sA, whose last reads were G1 MFMAs — all
        // fenced by B2). No race with concurrent sH1 reads (disjoint bytes).
#pragma unroll
        for (int p = 0; p < 2; ++p) {
            f32x4 bias = *(const f32x4*)&cano[256 + 32 * wave + 16 * p + 4 * quad];
#pragma unroll
            for (int q = 0; q < 4; ++q) {
                bf16x4 pv;
#pragma unroll
                for (int r = 0; r < 4; ++r)
                    pv[r] = (bf16)fmaxf(acc2[p][q][r] + bias[r], 0.f);
                *(bf16x4*)&sH2[(16 * q + l16) * SH2_STRIDE + 32 * wave + 16 * p + 4 * quad] = pv;
            }
        }
    }
    __syncthreads();                                         // B3

    // ------- GEMM3T: W3^T[64,128] x H2^T[128,64] -> sH3 -------
    f32x4 acc3[4];
#pragma unroll
    for (int q = 0; q < 4; ++q) acc3[q] = (f32x4){0.f, 0.f, 0.f, 0.f};
    const bf16* w3base = W3f + (size_t)wave * (4 * 512) + lane * 8;
#pragma unroll
    for (int ks = 0; ks < 4; ++ks) {
        bf16x8 w = *(const bf16x8*)(w3base + ks * 512);
#pragma unroll
        for (int q = 0; q < 4; ++q) {
            bf16x8 e = *(const bf16x8*)&sH2[(16 * q + l16) * SH2_STRIDE + ks * 32 + quad * 8];
            acc3[q] = __builtin_amdgcn_mfma_f32_16x16x32_bf16(w, e, acc3[q], 0, 0, 0);
        }
    }
    {   // writes sH3 @17408 (dead-sA bytes, disjoint from sH2 @0..17408 and
        // sH1 @41984): safe without a barrier before these writes.
        f32x4 bias = *(const f32x4*)&cano[384 + 16 * wave + 4 * quad];
#pragma unroll
        for (int q = 0; q < 4; ++q) {
            bf16x4 pv;
#pragma unroll
            for (int r = 0; r < 4; ++r)
                pv[r] = (bf16)fmaxf(acc3[q][r] + bias[r], 0.f);
            *(bf16x4*)&sH3[(16 * q + l16) * SH3_STRIDE + 16 * wave + 4 * quad] = pv;
        }
    }
    __syncthreads();                                         // B4

    // ---------------- Stage 4: h3[64] · W4 + b4 -> out (all threads) --------
    {
        int edge = tid >> 2;
        int part = tid & 3;
        int k0 = part * 16;
        const bf16* h = &sH3[edge * SH3_STRIDE + k0];   // 144B rows -> 16B aligned
        bf16x8 h0 = *(const bf16x8*)h;
        bf16x8 h1 = *(const bf16x8*)(h + 8);
        float s = 0.f;
#pragma unroll
        for (int k = 0; k < 8; ++k) s += (float)h0[k] * cano[452 + k0 + k];
#pragma unroll
        for (int k = 0; k < 8; ++k) s += (float)h1[k] * cano[452 + k0 + 8 + k];
        s += __shfl_xor(s, 1);
        s += __shfl_xor(s, 2);
        if (part == 0) out[e0 + edge] = s + cano[448];
    }
}

extern "C" void kernel_launch(void* const* d_in, const int* in_sizes, int n_in,
                              void* d_out, int out_size, void* d_ws, size_t ws_size,
                              hipStream_t stream) {
    const void* x  = d_in[0];
    const int*  ei = (const int*)d_in[1];
    const void* ef = d_in[2];
    const void* W1 = d_in[4];
    const void* b1 = d_in[5];
    const void* W2 = d_in[6];
    const void* b2 = d_in[7];
    const void* W3 = d_in[8];
    const void* b3 = d_in[9];
    const void* W4 = d_in[10];
    const void* b4 = d_in[11];
    float* out = (float*)d_out;

    char* ws = (char*)d_ws;
    const bool big = ws_size >= (size_t)WS_NEED;   // ws_size constant per session
    bf16* xbf   = (bf16*)ws;                       // BIG mode only
    char* wbase = big ? (ws + WS_XBF_BYTES) : ws;
    bf16*  W1f   = (bf16*)wbase;
    bf16*  W2f   = (bf16*)(wbase + WB_W2F);
    bf16*  W3f   = (bf16*)(wbase + WB_W3F);
    float* cano  = (float*)(wbase + WB_CANO);
    int*   flags = (int*)(wbase + WB_FLAG);

    sniff<<<1, 64, 0, stream>>>(x, ei, ef, W1, flags);
    canonicalize<<<483, 256, 0, stream>>>(W1, W2, W3, b1, b2, b3, W4, b4,
                                          W1f, W2f, W3f, cano, flags);
    if (big) convert_x<<<12500, 256, 0, stream>>>(x, xbf, flags);
    fused_mlp<<<E_TOTAL / 64, 256, 0, stream>>>(
        big ? (const void*)xbf : x, ei, ef, W1f, W2f, W3f,
        cano, flags, big ? 0 : -1, out);
}

// Round 6
// 612.520 us; speedup vs baseline: 2.5762x; 1.0515x over previous
//
#include <hip/hip_runtime.h>
#include <hip/hip_bf16.h>

typedef __bf16 bf16;
typedef __attribute__((ext_vector_type(8))) __bf16 bf16x8;
typedef __attribute__((ext_vector_type(4))) __bf16 bf16x4;
typedef __attribute__((ext_vector_type(4))) float f32x4;

#define E_TOTAL   1000000
#define NODE_DIM  128
#define EDGE_DIM  64

// LDS strides (bf16 elems): multiples of 8 (16B rows), ≡4 dwords mod 32 →
// 2-way bank aliasing only (free on gfx950, m136).
#define SA_STRIDE  328   // 320 + 8
#define SH1_STRIDE 264   // 256 + 8
#define SH2_STRIDE 136   // 128 + 8

// LDS plan — R2 anchor (R5 proved 3 blocks/CU matters post-epilogue-fix):
//   phase A: sA  @0      [64][328] = 41984 B
//   phase B: sH1 @0      [64][264] = 33792 B  (aliases sA; alias barrier)
//            sH2 @33792  [64][136] = 17408 B
//            sP  @51200  f32[64][4]=  1024 B  (stage4 cross-wave partials;
//                                             fresh region, no alias barrier)
// peak = 52224 B -> 3 blocks/CU (<= 54613).
#define SMEM_BYTES 52224
#define SH2_OFF    33792
#define SP_OFF     51200

// ws layout, BIG mode (ws_size >= WS_NEED):
//   [0, 25600000)  xbf bf16[100000*128]
//   then W1f (163840 B), W2f (65536), W3f (16384), cano fp32[516] (2064), flags (16)
// cano: [0,256) b1 | [256,384) b2 | [384,448) b3 | 448 b4 | 449..451 pad |
//       [452,516) W4  (452 ≡ 0 mod 4 -> f32x4-aligned loads)
// SMALL mode: same minus xbf, weights at offset 0.
#define WS_XBF_BYTES 25600000
#define WB_W2F  163840
#define WB_W3F  (163840 + 65536)
#define WB_CANO (163840 + 65536 + 16384)
#define WB_FLAG (163840 + 65536 + 16384 + 2064)
#define WB_END  (163840 + 65536 + 16384 + 2064 + 16)
#define WS_NEED (WS_XBF_BYTES + WB_END)

// ---------------------------------------------------------------------------
// Dtype sniffing (fp32 proven empirically; keep as runtime guard).
// ---------------------------------------------------------------------------
__device__ inline int plausible16(const unsigned short* h) {
    int c = 0;
    for (int i = 0; i < 64; ++i) {
        int e = (h[i] >> 7) & 0xFF;
        if (e >= 90 && e <= 151) ++c;
    }
    return c;
}

__global__ void sniff(const void* x, const void* ei, const void* ef,
                      const void* W1, int* flags) {
    if (threadIdx.x == 0 && blockIdx.x == 0) {
        flags[0] = (plausible16((const unsigned short*)x)  < 52) ? 1 : 0;
        flags[1] = (plausible16((const unsigned short*)ef) < 52) ? 1 : 0;
        flags[2] = (plausible16((const unsigned short*)W1) < 52) ? 1 : 0;
        const int* w = (const int*)ei;
        int oz = 0, lo_ok = 1;
        for (int i = 1; i < 32; i += 2) if (w[i] == 0) ++oz;
        for (int i = 0; i < 32; i += 2) if ((unsigned)w[i] >= 100000u) lo_ok = 0;
        flags[3] = (oz == 16 && lo_ok) ? 1 : 0;
    }
}

__device__ inline float loadF(const void* p, int isf, int i) {
    return isf ? ((const float*)p)[i] : (float)((const bf16*)p)[i];
}

// ---------------------------------------------------------------------------
// Weights -> frag-major: lane holds W^T[feat=jt*16+l16][k=ks*32+quad*8+jj];
// a wave's frag load is one coalesced 1KB stream.
// ---------------------------------------------------------------------------
__global__ void canonicalize(const void* W1, const void* W2, const void* W3,
                             const void* b1, const void* b2, const void* b3,
                             const void* W4, const void* b4,
                             bf16* W1f, bf16* W2f, bf16* W3f,
                             float* cano, const int* flags) {
    int isf = flags[2];
    int o = blockIdx.x * 256 + threadIdx.x;
    if (o < 81920) {                        // W1 [320][256] -> frag-major
        int jj = o & 7, lane = (o >> 3) & 63, t2 = o >> 9;
        int ks = t2 % 10, jt = t2 / 10;
        int k = ks * 32 + (lane >> 4) * 8 + jj;
        int n = jt * 16 + (lane & 15);
        W1f[o] = (bf16)loadF(W1, isf, k * 256 + n);
    } else if (o < 114688) {                // W2 [256][128]
        int o2 = o - 81920;
        int jj = o2 & 7, lane = (o2 >> 3) & 63, t2 = o2 >> 9;
        int ks = t2 & 7, jt = t2 >> 3;
        int k = ks * 32 + (lane >> 4) * 8 + jj;
        int n = jt * 16 + (lane & 15);
        W2f[o2] = (bf16)loadF(W2, isf, k * 128 + n);
    } else if (o < 122880) {                // W3 [128][64]
        int o3 = o - 114688;
        int jj = o3 & 7, lane = (o3 >> 3) & 63, t2 = o3 >> 9;
        int ks = t2 & 3, jt = t2 >> 2;
        int k = ks * 32 + (lane >> 4) * 8 + jj;
        int n = jt * 16 + (lane & 15);
        W3f[o3] = (bf16)loadF(W3, isf, k * 64 + n);
    } else if (o < 123396) {                // cano fp32: b1 b2 b3 b4 pad W4
        int j = o - 122880;
        float v;
        if (j < 256)       v = loadF(b1, isf, j);
        else if (j < 384)  v = loadF(b2, isf, j - 256);
        else if (j < 448)  v = loadF(b3, isf, j - 384);
        else if (j == 448) v = loadF(b4, isf, 0);
        else if (j < 452)  v = 0.f;                    // pad for W4 alignment
        else               v = loadF(W4, isf, j - 452);
        cano[j] = v;
    }
}

// x -> bf16 (halves gather bytes; x_bf16 = 25.6 MB ≈ L2-aggregate scale).
__global__ void convert_x(const void* x, bf16* xbf, const int* flags) {
    int i = (blockIdx.x * 256 + threadIdx.x) * 4;   // 12500 blocks covers 12.8M
    if (flags[0]) {
        const float* f = (const float*)x + i;
        bf16 v0 = (bf16)f[0], v1 = (bf16)f[1], v2 = (bf16)f[2], v3 = (bf16)f[3];
        xbf[i] = v0; xbf[i + 1] = v1; xbf[i + 2] = v2; xbf[i + 3] = v3;
    } else {
        *(unsigned long long*)(xbf + i) = *(const unsigned long long*)((const bf16*)x + i);
    }
}

// ---------------------------------------------------------------------------
// Fused MLP, TRANSPOSED chain (H^T = W^T · A^T per layer).
//   MFMA 16x16x32 bf16: A: lane holds A[m=l16][k=quad*8+j]
//                       B: lane holds B[k=quad*8+j][n=l16]
//                       C/D: reg r = D[row=quad*4+r][col=l16]
// G1/G2 feature-sliced; G3 feature-sliced WITHOUT the sH3 round-trip:
// stage4 is fused onto acc3 via quad-reduction (shfl_xor 16/32) + a 1KB f32
// cross-wave partial buffer sP (1 ds_write_b32/thread, 1 b128 read per 4).
// Cross-barrier weight prefetch: ks=0 weight frags for the NEXT GEMM are
// issued before each __syncthreads (loads drain complete at the barrier;
// their L2 latency hides under epilogue+barrier instead of phase start).
// s_setprio(1) around MFMA nests (3 independent blocks/CU = m191 regime).
// ---------------------------------------------------------------------------
__global__ __launch_bounds__(256, 3) void fused_mlp(
    const void* __restrict__ xs, const int* __restrict__ ei, const void* __restrict__ ef,
    const bf16* __restrict__ W1f, const bf16* __restrict__ W2f,
    const bf16* __restrict__ W3f,
    const float* __restrict__ cano, const int* __restrict__ flags,
    int xmode_host, float* __restrict__ out)
{
    __shared__ __align__(16) char smem[SMEM_BYTES];
    bf16*  sA  = (bf16*)smem;                 // phase A: [64][328]
    bf16*  sH1 = (bf16*)smem;                 // phase B: [64][264] aliases dead sA
    bf16*  sH2 = (bf16*)(smem + SH2_OFF);     // [64][136]
    float* sP  = (float*)(smem + SP_OFF);     // [64][4] f32 partials (fresh)

    const int tid  = threadIdx.x;
    const int wave = tid >> 6;
    const int lane = tid & 63;
    const int quad = lane >> 4;
    const int l16  = lane & 15;
    const int e0   = blockIdx.x * 64;

    const int isfe = flags[1];
    const int is64 = flags[3];
    const int xm   = (xmode_host < 0) ? flags[0] : xmode_host;

    const bf16* w1base = W1f + (size_t)wave * (40 * 512) + lane * 8;
    const bf16* w2base = W2f + (size_t)wave * (16 * 512) + lane * 8;
    const bf16* w3base = W3f + (size_t)wave * (4 * 512) + lane * 8;

    // ---- stage full A-tile: x = 8 tasks/thread, ef = 2 tasks/thread ----
    {
        const int xrow0 = tid >> 5;          // rows i*8 + xrow0
        const int xseg  = tid & 31;          // k = xseg*8 (0..255)
        const int which = xseg >> 4;         // 0: v-endpoint, 1: u-endpoint
        const int xk    = (xseg & 15) << 3;  // k within node row
        if (xm == 0) {
            const bf16* xsb = (const bf16*)xs;
            bf16x8 xb[8];
#pragma unroll
            for (int i = 0; i < 8; ++i) {
                int row = i * 8 + xrow0;
                size_t pos = which ? (size_t)(E_TOTAL + e0 + row) : (size_t)(e0 + row);
                int node = is64 ? ei[2 * pos] : ei[pos];
                xb[i] = *(const bf16x8*)(xsb + (size_t)node * NODE_DIM + xk);
            }
#pragma unroll
            for (int i = 0; i < 8; ++i)
                *(bf16x8*)&sA[(i * 8 + xrow0) * SA_STRIDE + xseg * 8] = xb[i];
        } else {
            const float* xsf = (const float*)xs;
            float xf[8][8];
#pragma unroll
            for (int i = 0; i < 8; ++i) {
                int row = i * 8 + xrow0;
                size_t pos = which ? (size_t)(E_TOTAL + e0 + row) : (size_t)(e0 + row);
                int node = is64 ? ei[2 * pos] : ei[pos];
                const float* f = xsf + (size_t)node * NODE_DIM + xk;
#pragma unroll
                for (int j = 0; j < 8; ++j) xf[i][j] = f[j];
            }
#pragma unroll
            for (int i = 0; i < 8; ++i) {
                bf16x8 v;
#pragma unroll
                for (int j = 0; j < 8; ++j) v[j] = (bf16)xf[i][j];
                *(bf16x8*)&sA[(i * 8 + xrow0) * SA_STRIDE + xseg * 8] = v;
            }
        }
        // edge features: rows tid>>3 and +32, k = 256 + (tid&7)*8
        int seg = tid & 7, r0 = tid >> 3, r1 = r0 + 32;
        int kst = 256 + seg * 8;
        if (isfe) {
            const float* f0 = (const float*)ef + (size_t)(e0 + r0) * EDGE_DIM + seg * 8;
            const float* f1 = (const float*)ef + (size_t)(e0 + r1) * EDGE_DIM + seg * 8;
            float a0[8], a1[8];
#pragma unroll
            for (int j = 0; j < 8; ++j) { a0[j] = f0[j]; a1[j] = f1[j]; }
            bf16x8 v0, v1;
#pragma unroll
            for (int j = 0; j < 8; ++j) { v0[j] = (bf16)a0[j]; v1[j] = (bf16)a1[j]; }
            *(bf16x8*)&sA[r0 * SA_STRIDE + kst] = v0;
            *(bf16x8*)&sA[r1 * SA_STRIDE + kst] = v1;
        } else {
            const bf16* eb = (const bf16*)ef;
            bf16x8 v0 = *(const bf16x8*)(eb + (size_t)(e0 + r0) * EDGE_DIM + seg * 8);
            bf16x8 v1 = *(const bf16x8*)(eb + (size_t)(e0 + r1) * EDGE_DIM + seg * 8);
            *(bf16x8*)&sA[r0 * SA_STRIDE + kst] = v0;
            *(bf16x8*)&sA[r1 * SA_STRIDE + kst] = v1;
        }
    }
    // prefetch G1 ks=0 weight frags before the barrier (drain-complete there)
    bf16x8 w1pre[4];
#pragma unroll
    for (int p = 0; p < 4; ++p)
        w1pre[p] = *(const bf16x8*)(w1base + (p * 10 + 0) * 512);
    __syncthreads();                                         // B1

    // ------- GEMM1T: W1^T[256,320] x A^T[320,64] -> sH1 (edge-major) -------
    f32x4 acc1[4][4];
#pragma unroll
    for (int p = 0; p < 4; ++p)
#pragma unroll
        for (int q = 0; q < 4; ++q)
            acc1[p][q] = (f32x4){0.f, 0.f, 0.f, 0.f};

#pragma unroll
    for (int ks = 0; ks < 10; ++ks) {
        bf16x8 w[4], e[4];
#pragma unroll
        for (int p = 0; p < 4; ++p)
            w[p] = (ks == 0) ? w1pre[p]
                             : *(const bf16x8*)(w1base + (p * 10 + ks) * 512);
#pragma unroll
        for (int q = 0; q < 4; ++q)
            e[q] = *(const bf16x8*)&sA[(16 * q + l16) * SA_STRIDE + ks * 32 + quad * 8];
        __builtin_amdgcn_s_setprio(1);
#pragma unroll
        for (int p = 0; p < 4; ++p)
#pragma unroll
            for (int q = 0; q < 4; ++q)
                acc1[p][q] = __builtin_amdgcn_mfma_f32_16x16x32_bf16(
                    w[p], e[q], acc1[p][q], 0, 0, 0);
        __builtin_amdgcn_s_setprio(0);
    }
    // sA fully consumed by ALL waves before sH1 (same bytes) is written.
    __syncthreads();                                         // B1.5 (alias)
    {   // bias + relu -> sH1[edge][feat], packed b64
#pragma unroll
        for (int p = 0; p < 4; ++p) {
            f32x4 bias = *(const f32x4*)&cano[64 * wave + 16 * p + 4 * quad];
#pragma unroll
            for (int q = 0; q < 4; ++q) {
                bf16x4 pv;
#pragma unroll
                for (int r = 0; r < 4; ++r)
                    pv[r] = (bf16)fmaxf(acc1[p][q][r] + bias[r], 0.f);
                *(bf16x4*)&sH1[(16 * q + l16) * SH1_STRIDE + 64 * wave + 16 * p + 4 * quad] = pv;
            }
        }
    }
    // prefetch G2 ks=0 weight frags before the barrier
    bf16x8 w2pre[2];
#pragma unroll
    for (int p = 0; p < 2; ++p)
        w2pre[p] = *(const bf16x8*)(w2base + (p * 8 + 0) * 512);
    __syncthreads();                                         // B2

    // ------- GEMM2T: W2^T[128,256] x H1^T[256,64] -> sH2 -------
    f32x4 acc2[2][4];
#pragma unroll
    for (int p = 0; p < 2; ++p)
#pragma unroll
        for (int q = 0; q < 4; ++q)
            acc2[p][q] = (f32x4){0.f, 0.f, 0.f, 0.f};
#pragma unroll
    for (int ks = 0; ks < 8; ++ks) {
        bf16x8 w[2], e[4];
#pragma unroll
        for (int p = 0; p < 2; ++p)
            w[p] = (ks == 0) ? w2pre[p]
                             : *(const bf16x8*)(w2base + (p * 8 + ks) * 512);
#pragma unroll
        for (int q = 0; q < 4; ++q)
            e[q] = *(const bf16x8*)&sH1[(16 * q + l16) * SH1_STRIDE + ks * 32 + quad * 8];
        __builtin_amdgcn_s_setprio(1);
#pragma unroll
        for (int p = 0; p < 2; ++p)
#pragma unroll
            for (int q = 0; q < 4; ++q)
                acc2[p][q] = __builtin_amdgcn_mfma_f32_16x16x32_bf16(
                    w[p], e[q], acc2[p][q], 0, 0, 0);
        __builtin_amdgcn_s_setprio(0);
    }
    {   // sH2 is a fresh region (no alias with live sH1) — no extra barrier.
#pragma unroll
        for (int p = 0; p < 2; ++p) {
            f32x4 bias = *(const f32x4*)&cano[256 + 32 * wave + 16 * p + 4 * quad];
#pragma unroll
            for (int q = 0; q < 4; ++q) {
                bf16x4 pv;
#pragma unroll
                for (int r = 0; r < 4; ++r)
                    pv[r] = (bf16)fmaxf(acc2[p][q][r] + bias[r], 0.f);
                *(bf16x4*)&sH2[(16 * q + l16) * SH2_STRIDE + 32 * wave + 16 * p + 4 * quad] = pv;
            }
        }
    }
    // prefetch G3 ks=0 weight frag before the barrier
    bf16x8 w3pre = *(const bf16x8*)(w3base + 0 * 512);
    __syncthreads();                                         // B3

    // ------- GEMM3T: W3^T[64,128] x H2^T[128,64], feature-sliced -------
    // wave owns feats 16*wave + (4*quad + r); edge = 16*q + l16.
    f32x4 acc3[4];
#pragma unroll
    for (int q = 0; q < 4; ++q) acc3[q] = (f32x4){0.f, 0.f, 0.f, 0.f};
#pragma unroll
    for (int ks = 0; ks < 4; ++ks) {
        bf16x8 w = (ks == 0) ? w3pre : *(const bf16x8*)(w3base + ks * 512);
        bf16x8 e[4];
#pragma unroll
        for (int q = 0; q < 4; ++q)
            e[q] = *(const bf16x8*)&sH2[(16 * q + l16) * SH2_STRIDE + ks * 32 + quad * 8];
        __builtin_amdgcn_s_setprio(1);
#pragma unroll
        for (int q = 0; q < 4; ++q)
            acc3[q] = __builtin_amdgcn_mfma_f32_16x16x32_bf16(w, e[q], acc3[q], 0, 0, 0);
        __builtin_amdgcn_s_setprio(0);
    }

    // ---- Stage 4 fused on acc3: per-wave 16-feat partial of h3·W4, then
    // quad-reduce (shfl_xor 16/32) and one f32 write to sP[edge][wave].
    // No sH3 round-trip (removes 4 b64 writes + 2 b128 reads + 2 VALU passes).
    {
        f32x4 b3v = *(const f32x4*)&cano[384 + 16 * wave + 4 * quad];
        f32x4 w4v = *(const f32x4*)&cano[452 + 16 * wave + 4 * quad];
        float pq[4];
#pragma unroll
        for (int q = 0; q < 4; ++q) {
            float s = 0.f;
#pragma unroll
            for (int r = 0; r < 4; ++r)
                s += fmaxf(acc3[q][r] + b3v[r], 0.f) * w4v[r];
            s += __shfl_xor(s, 16);      // + partner quad^1
            s += __shfl_xor(s, 32);      // + partner quad^2
            pq[q] = s;                   // full 16-feat wave partial, edge 16q+l16
        }
        // lane (quad,l16) writes edge 16*quad+l16's partial (static select)
        float mine = (quad == 0) ? pq[0] : (quad == 1) ? pq[1]
                   : (quad == 2) ? pq[2] : pq[3];
        sP[(16 * quad + l16) * 4 + wave] = mine;
    }
    __syncthreads();                                         // B4

    // ---- combine 4 wave partials per edge, add b4, store ----
    if (tid < 64) {
        f32x4 v = *(const f32x4*)&sP[tid * 4];
        out[e0 + tid] = v[0] + v[1] + v[2] + v[3] + cano[448];
    }
}

extern "C" void kernel_launch(void* const* d_in, const int* in_sizes, int n_in,
                              void* d_out, int out_size, void* d_ws, size_t ws_size,
                              hipStream_t stream) {
    const void* x  = d_in[0];
    const int*  ei = (const int*)d_in[1];
    const void* ef = d_in[2];
    const void* W1 = d_in[4];
    const void* b1 = d_in[5];
    const void* W2 = d_in[6];
    const void* b2 = d_in[7];
    const void* W3 = d_in[8];
    const void* b3 = d_in[9];
    const void* W4 = d_in[10];
    const void* b4 = d_in[11];
    float* out = (float*)d_out;

    char* ws = (char*)d_ws;
    const bool big = ws_size >= (size_t)WS_NEED;   // ws_size constant per session
    bf16* xbf   = (bf16*)ws;                       // BIG mode only
    char* wbase = big ? (ws + WS_XBF_BYTES) : ws;
    bf16*  W1f   = (bf16*)wbase;
    bf16*  W2f   = (bf16*)(wbase + WB_W2F);
    bf16*  W3f   = (bf16*)(wbase + WB_W3F);
    float* cano  = (float*)(wbase + WB_CANO);
    int*   flags = (int*)(wbase + WB_FLAG);

    sniff<<<1, 64, 0, stream>>>(x, ei, ef, W1, flags);
    canonicalize<<<483, 256, 0, stream>>>(W1, W2, W3, b1, b2, b3, W4, b4,
                                          W1f, W2f, W3f, cano, flags);
    if (big) convert_x<<<12500, 256, 0, stream>>>(x, xbf, flags);
    fused_mlp<<<E_TOTAL / 64, 256, 0, stream>>>(
        big ? (const void*)xbf : x, ei, ef, W1f, W2f, W3f,
        cano, flags, big ? 0 : -1, out);
}

// Round 7
// 599.398 us; speedup vs baseline: 2.6326x; 1.0219x over previous
//
#include <hip/hip_runtime.h>
#include <hip/hip_bf16.h>

typedef __bf16 bf16;
typedef __attribute__((ext_vector_type(8))) __bf16 bf16x8;
typedef __attribute__((ext_vector_type(4))) __bf16 bf16x4;
typedef __attribute__((ext_vector_type(4))) float f32x4;

#define E_TOTAL   1000000
#define NODE_DIM  128
#define EDGE_DIM  64

// LDS strides (bf16 elems): multiples of 8 (16B rows), ≡4 dwords mod 32 →
// 2-way bank aliasing only (free on gfx950, m136).
#define SA_STRIDE  328   // 320 + 8
#define SH1_STRIDE 264   // 256 + 8
#define SH2_STRIDE 136   // 128 + 8

// LDS plan (R2/R6 anchor — 3 blocks/CU proven to matter post-epilogue-fix):
//   phase A: sA  @0      [64][328] = 41984 B
//   phase B: sH1 @0      [64][264] = 33792 B  (aliases sA; alias barrier)
//            sH2 @33792  [64][136] = 17408 B
//            sP  @51200  f32[64][4]=  1024 B  (stage4 cross-wave partials)
// peak = 52224 B -> 3 blocks/CU (<= 54613).
#define SMEM_BYTES 52224
#define SH2_OFF    33792
#define SP_OFF     51200

// ws layout, BIG mode (ws_size >= WS_NEED):
//   [0, 25600000)  xbf bf16[100000*128]
//   then W1f (163840 B), W2f (65536), W3f (16384), cano fp32[516] (2064), pad (16)
// cano: [0,256) b1 | [256,384) b2 | [384,448) b3 | 448 b4 | 449..451 pad |
//       [452,516) W4  (452 ≡ 0 mod 4 -> f32x4-aligned loads)
// SMALL mode: same minus xbf, weights at offset 0.
#define WS_XBF_BYTES 25600000
#define WB_W2F  163840
#define WB_W3F  (163840 + 65536)
#define WB_CANO (163840 + 65536 + 16384)
#define WB_END  (163840 + 65536 + 16384 + 2064 + 16)
#define WS_NEED (WS_XBF_BYTES + WB_END)

// ---------------------------------------------------------------------------
// Wave-parallel dtype sniff (replaces the single-threaded sniff kernel):
// 64 lanes each classify one 16-bit word, ballot, count. Same semantics as
// the serial plausible16 (<52 bf16-plausible exponents in first 64 => fp32).
// Every wave computes it redundantly from the same (L2-hot) 128 bytes.
// ---------------------------------------------------------------------------
__device__ inline int wave_is_f32(const void* p, int lane) {
    unsigned short h = ((const unsigned short*)p)[lane];
    int e = (h >> 7) & 0xFF;
    unsigned long long b = __ballot(e >= 90 && e <= 151);
    return (__popcll(b) < 52) ? 1 : 0;
}

// ei width sniff: first 32 ints; odd words all zero AND even words < 100000
// => int64 indices. Lanes >= 32 vote true (neutral).
__device__ inline int wave_is_i64(const int* ei, int lane) {
    int ok = 1;
    if (lane < 32) {
        int v = ei[lane];
        ok = (lane & 1) ? (v == 0) : ((unsigned)v < 100000u);
    }
    unsigned long long b = __ballot(ok);
    return (b == ~0ull) ? 1 : 0;
}

__device__ inline float loadF(const void* p, int isf, int i) {
    return isf ? ((const float*)p)[i] : (float)((const bf16*)p)[i];
}

// ---------------------------------------------------------------------------
// Weights -> frag-major: lane holds W^T[feat=jt*16+l16][k=ks*32+quad*8+jj];
// a wave's frag load is one coalesced 1KB stream. Self-sniffs W1 dtype.
// ---------------------------------------------------------------------------
__global__ void canonicalize(const void* W1, const void* W2, const void* W3,
                             const void* b1, const void* b2, const void* b3,
                             const void* W4, const void* b4,
                             bf16* W1f, bf16* W2f, bf16* W3f, float* cano) {
    int isf = wave_is_f32(W1, threadIdx.x & 63);
    int o = blockIdx.x * 256 + threadIdx.x;
    if (o < 81920) {                        // W1 [320][256] -> frag-major
        int jj = o & 7, lane = (o >> 3) & 63, t2 = o >> 9;
        int ks = t2 % 10, jt = t2 / 10;
        int k = ks * 32 + (lane >> 4) * 8 + jj;
        int n = jt * 16 + (lane & 15);
        W1f[o] = (bf16)loadF(W1, isf, k * 256 + n);
    } else if (o < 114688) {                // W2 [256][128]
        int o2 = o - 81920;
        int jj = o2 & 7, lane = (o2 >> 3) & 63, t2 = o2 >> 9;
        int ks = t2 & 7, jt = t2 >> 3;
        int k = ks * 32 + (lane >> 4) * 8 + jj;
        int n = jt * 16 + (lane & 15);
        W2f[o2] = (bf16)loadF(W2, isf, k * 128 + n);
    } else if (o < 122880) {                // W3 [128][64]
        int o3 = o - 114688;
        int jj = o3 & 7, lane = (o3 >> 3) & 63, t2 = o3 >> 9;
        int ks = t2 & 3, jt = t2 >> 2;
        int k = ks * 32 + (lane >> 4) * 8 + jj;
        int n = jt * 16 + (lane & 15);
        W3f[o3] = (bf16)loadF(W3, isf, k * 64 + n);
    } else if (o < 123396) {                // cano fp32: b1 b2 b3 b4 pad W4
        int j = o - 122880;
        float v;
        if (j < 256)       v = loadF(b1, isf, j);
        else if (j < 384)  v = loadF(b2, isf, j - 256);
        else if (j < 448)  v = loadF(b3, isf, j - 384);
        else if (j == 448) v = loadF(b4, isf, 0);
        else if (j < 452)  v = 0.f;                    // pad for W4 alignment
        else               v = loadF(W4, isf, j - 452);
        cano[j] = v;
    }
}

// x -> bf16, 8 elems/thread, f32x4 x2 loads + one 16B store. Self-sniffs x.
// 6250 blocks x 256 threads x 8 = 12.8M elems.
__global__ void convert_x(const void* x, bf16* xbf) {
    int isf = wave_is_f32(x, threadIdx.x & 63);
    size_t i = ((size_t)blockIdx.x * 256 + threadIdx.x) * 8;
    if (isf) {
        const float* f = (const float*)x + i;
        f32x4 a = *(const f32x4*)f;
        f32x4 c = *(const f32x4*)(f + 4);
        bf16x8 v;
#pragma unroll
        for (int j = 0; j < 4; ++j) { v[j] = (bf16)a[j]; v[j + 4] = (bf16)c[j]; }
        *(bf16x8*)(xbf + i) = v;
    } else {
        *(bf16x8*)(xbf + i) = *(const bf16x8*)((const bf16*)x + i);
    }
}

// ---------------------------------------------------------------------------
// Fused MLP, TRANSPOSED chain (H^T = W^T · A^T per layer).
//   MFMA 16x16x32 bf16: A: lane holds A[m=l16][k=quad*8+j]
//                       B: lane holds B[k=quad*8+j][n=l16]
//                       C/D: reg r = D[row=quad*4+r][col=l16]
// G1/G2 feature-sliced; G3 feature-sliced with stage4 fused on acc3
// (quad shfl_xor reduce + 1KB sP partial buffer — R6, +25us).
// Cross-barrier weight prefetch (R6 proven, extended): G1 ks=0,1 issued
// before B1; ALL 16 G2 frags before B2 (acc1 dead -> reg headroom); all 4
// G3 frags before B3. G2/G3 loops are pure LDS+MFMA. Self-sniffs ef/ei
// (and x in SMALL mode) — no sniff dispatch, no flag dependency.
// s_setprio(1) around MFMA nests (3 independent blocks/CU = m191 regime).
// ---------------------------------------------------------------------------
__global__ __launch_bounds__(256, 3) void fused_mlp(
    const void* __restrict__ xs, const int* __restrict__ ei, const void* __restrict__ ef,
    const bf16* __restrict__ W1f, const bf16* __restrict__ W2f,
    const bf16* __restrict__ W3f,
    const float* __restrict__ cano,
    int xmode_host, float* __restrict__ out)
{
    __shared__ __align__(16) char smem[SMEM_BYTES];
    bf16*  sA  = (bf16*)smem;                 // phase A: [64][328]
    bf16*  sH1 = (bf16*)smem;                 // phase B: [64][264] aliases dead sA
    bf16*  sH2 = (bf16*)(smem + SH2_OFF);     // [64][136]
    float* sP  = (float*)(smem + SP_OFF);     // [64][4] f32 partials (fresh)

    const int tid  = threadIdx.x;
    const int wave = tid >> 6;
    const int lane = tid & 63;
    const int quad = lane >> 4;
    const int l16  = lane & 15;
    const int e0   = blockIdx.x * 64;

    // self-sniff (wave-parallel, ~300cy, L2-hot after first blocks)
    const int isfe = wave_is_f32(ef, lane);
    const int is64 = wave_is_i64(ei, lane);
    const int xm   = (xmode_host >= 0) ? xmode_host : wave_is_f32(xs, lane);

    const bf16* w1base = W1f + (size_t)wave * (40 * 512) + lane * 8;
    const bf16* w2base = W2f + (size_t)wave * (16 * 512) + lane * 8;
    const bf16* w3base = W3f + (size_t)wave * (4 * 512) + lane * 8;

    // ---- stage full A-tile: x = 8 tasks/thread, ef = 2 tasks/thread ----
    {
        const int xrow0 = tid >> 5;          // rows i*8 + xrow0
        const int xseg  = tid & 31;          // k = xseg*8 (0..255)
        const int which = xseg >> 4;         // 0: v-endpoint, 1: u-endpoint
        const int xk    = (xseg & 15) << 3;  // k within node row
        if (xm == 0) {
            const bf16* xsb = (const bf16*)xs;
            bf16x8 xb[8];
#pragma unroll
            for (int i = 0; i < 8; ++i) {
                int row = i * 8 + xrow0;
                size_t pos = which ? (size_t)(E_TOTAL + e0 + row) : (size_t)(e0 + row);
                int node = is64 ? ei[2 * pos] : ei[pos];
                xb[i] = *(const bf16x8*)(xsb + (size_t)node * NODE_DIM + xk);
            }
#pragma unroll
            for (int i = 0; i < 8; ++i)
                *(bf16x8*)&sA[(i * 8 + xrow0) * SA_STRIDE + xseg * 8] = xb[i];
        } else {
            const float* xsf = (const float*)xs;
            float xf[8][8];
#pragma unroll
            for (int i = 0; i < 8; ++i) {
                int row = i * 8 + xrow0;
                size_t pos = which ? (size_t)(E_TOTAL + e0 + row) : (size_t)(e0 + row);
                int node = is64 ? ei[2 * pos] : ei[pos];
                const float* f = xsf + (size_t)node * NODE_DIM + xk;
#pragma unroll
                for (int j = 0; j < 8; ++j) xf[i][j] = f[j];
            }
#pragma unroll
            for (int i = 0; i < 8; ++i) {
                bf16x8 v;
#pragma unroll
                for (int j = 0; j < 8; ++j) v[j] = (bf16)xf[i][j];
                *(bf16x8*)&sA[(i * 8 + xrow0) * SA_STRIDE + xseg * 8] = v;
            }
        }
        // edge features: rows tid>>3 and +32, k = 256 + (tid&7)*8
        int seg = tid & 7, r0 = tid >> 3, r1 = r0 + 32;
        int kst = 256 + seg * 8;
        if (isfe) {
            const float* f0 = (const float*)ef + (size_t)(e0 + r0) * EDGE_DIM + seg * 8;
            const float* f1 = (const float*)ef + (size_t)(e0 + r1) * EDGE_DIM + seg * 8;
            float a0[8], a1[8];
#pragma unroll
            for (int j = 0; j < 8; ++j) { a0[j] = f0[j]; a1[j] = f1[j]; }
            bf16x8 v0, v1;
#pragma unroll
            for (int j = 0; j < 8; ++j) { v0[j] = (bf16)a0[j]; v1[j] = (bf16)a1[j]; }
            *(bf16x8*)&sA[r0 * SA_STRIDE + kst] = v0;
            *(bf16x8*)&sA[r1 * SA_STRIDE + kst] = v1;
        } else {
            const bf16* eb = (const bf16*)ef;
            bf16x8 v0 = *(const bf16x8*)(eb + (size_t)(e0 + r0) * EDGE_DIM + seg * 8);
            bf16x8 v1 = *(const bf16x8*)(eb + (size_t)(e0 + r1) * EDGE_DIM + seg * 8);
            *(bf16x8*)&sA[r0 * SA_STRIDE + kst] = v0;
            *(bf16x8*)&sA[r1 * SA_STRIDE + kst] = v1;
        }
    }
    // prefetch G1 ks=0,1 weight frags before the barrier (drain-complete at B1)
    bf16x8 w1pre[2][4];
#pragma unroll
    for (int ks = 0; ks < 2; ++ks)
#pragma unroll
        for (int p = 0; p < 4; ++p)
            w1pre[ks][p] = *(const bf16x8*)(w1base + (p * 10 + ks) * 512);
    __syncthreads();                                         // B1

    // ------- GEMM1T: W1^T[256,320] x A^T[320,64] -> sH1 (edge-major) -------
    f32x4 acc1[4][4];
#pragma unroll
    for (int p = 0; p < 4; ++p)
#pragma unroll
        for (int q = 0; q < 4; ++q)
            acc1[p][q] = (f32x4){0.f, 0.f, 0.f, 0.f};

#pragma unroll
    for (int ks = 0; ks < 10; ++ks) {
        bf16x8 w[4], e[4];
#pragma unroll
        for (int p = 0; p < 4; ++p)
            w[p] = (ks < 2) ? w1pre[ks][p]
                            : *(const bf16x8*)(w1base + (p * 10 + ks) * 512);
#pragma unroll
        for (int q = 0; q < 4; ++q)
            e[q] = *(const bf16x8*)&sA[(16 * q + l16) * SA_STRIDE + ks * 32 + quad * 8];
        __builtin_amdgcn_s_setprio(1);
#pragma unroll
        for (int p = 0; p < 4; ++p)
#pragma unroll
            for (int q = 0; q < 4; ++q)
                acc1[p][q] = __builtin_amdgcn_mfma_f32_16x16x32_bf16(
                    w[p], e[q], acc1[p][q], 0, 0, 0);
        __builtin_amdgcn_s_setprio(0);
    }
    // sA fully consumed by ALL waves before sH1 (same bytes) is written.
    __syncthreads();                                         // B1.5 (alias)
    // prefetch ALL G2 weight frags (16 x 16B = 64 regs; acc1 is dying here,
    // so peak pressure stays under the 3-waves/SIMD budget of 170)
    bf16x8 w2pre[2][8];
#pragma unroll
    for (int p = 0; p < 2; ++p)
#pragma unroll
        for (int ks = 0; ks < 8; ++ks)
            w2pre[p][ks] = *(const bf16x8*)(w2base + (p * 8 + ks) * 512);
    {   // bias + relu -> sH1[edge][feat], packed b64
#pragma unroll
        for (int p = 0; p < 4; ++p) {
            f32x4 bias = *(const f32x4*)&cano[64 * wave + 16 * p + 4 * quad];
#pragma unroll
            for (int q = 0; q < 4; ++q) {
                bf16x4 pv;
#pragma unroll
                for (int r = 0; r < 4; ++r)
                    pv[r] = (bf16)fmaxf(acc1[p][q][r] + bias[r], 0.f);
                *(bf16x4*)&sH1[(16 * q + l16) * SH1_STRIDE + 64 * wave + 16 * p + 4 * quad] = pv;
            }
        }
    }
    __syncthreads();                                         // B2

    // ------- GEMM2T: W2^T[128,256] x H1^T[256,64] -> sH2 (pure LDS+MFMA) ---
    f32x4 acc2[2][4];
#pragma unroll
    for (int p = 0; p < 2; ++p)
#pragma unroll
        for (int q = 0; q < 4; ++q)
            acc2[p][q] = (f32x4){0.f, 0.f, 0.f, 0.f};
#pragma unroll
    for (int ks = 0; ks < 8; ++ks) {
        bf16x8 e[4];
#pragma unroll
        for (int q = 0; q < 4; ++q)
            e[q] = *(const bf16x8*)&sH1[(16 * q + l16) * SH1_STRIDE + ks * 32 + quad * 8];
        __builtin_amdgcn_s_setprio(1);
#pragma unroll
        for (int p = 0; p < 2; ++p)
#pragma unroll
            for (int q = 0; q < 4; ++q)
                acc2[p][q] = __builtin_amdgcn_mfma_f32_16x16x32_bf16(
                    w2pre[p][ks], e[q], acc2[p][q], 0, 0, 0);
        __builtin_amdgcn_s_setprio(0);
    }
    // prefetch all 4 G3 weight frags (16 regs) while epilogue runs
    bf16x8 w3pre[4];
#pragma unroll
    for (int ks = 0; ks < 4; ++ks)
        w3pre[ks] = *(const bf16x8*)(w3base + ks * 512);
    {   // sH2 is a fresh region (no alias with live sH1) — no extra barrier.
#pragma unroll
        for (int p = 0; p < 2; ++p) {
            f32x4 bias = *(const f32x4*)&cano[256 + 32 * wave + 16 * p + 4 * quad];
#pragma unroll
            for (int q = 0; q < 4; ++q) {
                bf16x4 pv;
#pragma unroll
                for (int r = 0; r < 4; ++r)
                    pv[r] = (bf16)fmaxf(acc2[p][q][r] + bias[r], 0.f);
                *(bf16x4*)&sH2[(16 * q + l16) * SH2_STRIDE + 32 * wave + 16 * p + 4 * quad] = pv;
            }
        }
    }
    __syncthreads();                                         // B3

    // ------- GEMM3T: W3^T[64,128] x H2^T[128,64] (pure LDS+MFMA) -------
    f32x4 acc3[4];
#pragma unroll
    for (int q = 0; q < 4; ++q) acc3[q] = (f32x4){0.f, 0.f, 0.f, 0.f};
#pragma unroll
    for (int ks = 0; ks < 4; ++ks) {
        bf16x8 e[4];
#pragma unroll
        for (int q = 0; q < 4; ++q)
            e[q] = *(const bf16x8*)&sH2[(16 * q + l16) * SH2_STRIDE + ks * 32 + quad * 8];
        __builtin_amdgcn_s_setprio(1);
#pragma unroll
        for (int q = 0; q < 4; ++q)
            acc3[q] = __builtin_amdgcn_mfma_f32_16x16x32_bf16(w3pre[ks], e[q], acc3[q], 0, 0, 0);
        __builtin_amdgcn_s_setprio(0);
    }

    // ---- Stage 4 fused on acc3: per-wave 16-feat partial of h3·W4, then
    // quad-reduce (shfl_xor 16/32) and one f32 write to sP[edge][wave].
    {
        f32x4 b3v = *(const f32x4*)&cano[384 + 16 * wave + 4 * quad];
        f32x4 w4v = *(const f32x4*)&cano[452 + 16 * wave + 4 * quad];
        float pq[4];
#pragma unroll
        for (int q = 0; q < 4; ++q) {
            float s = 0.f;
#pragma unroll
            for (int r = 0; r < 4; ++r)
                s += fmaxf(acc3[q][r] + b3v[r], 0.f) * w4v[r];
            s += __shfl_xor(s, 16);      // + partner quad^1
            s += __shfl_xor(s, 32);      // + partner quad^2
            pq[q] = s;                   // full 16-feat wave partial, edge 16q+l16
        }
        // lane (quad,l16) writes edge 16*quad+l16's partial (static select)
        float mine = (quad == 0) ? pq[0] : (quad == 1) ? pq[1]
                   : (quad == 2) ? pq[2] : pq[3];
        sP[(16 * quad + l16) * 4 + wave] = mine;
    }
    __syncthreads();                                         // B4

    // ---- combine 4 wave partials per edge, add b4, store ----
    if (tid < 64) {
        f32x4 v = *(const f32x4*)&sP[tid * 4];
        out[e0 + tid] = v[0] + v[1] + v[2] + v[3] + cano[448];
    }
}

extern "C" void kernel_launch(void* const* d_in, const int* in_sizes, int n_in,
                              void* d_out, int out_size, void* d_ws, size_t ws_size,
                              hipStream_t stream) {
    const void* x  = d_in[0];
    const int*  ei = (const int*)d_in[1];
    const void* ef = d_in[2];
    const void* W1 = d_in[4];
    const void* b1 = d_in[5];
    const void* W2 = d_in[6];
    const void* b2 = d_in[7];
    const void* W3 = d_in[8];
    const void* b3 = d_in[9];
    const void* W4 = d_in[10];
    const void* b4 = d_in[11];
    float* out = (float*)d_out;

    char* ws = (char*)d_ws;
    const bool big = ws_size >= (size_t)WS_NEED;   // ws_size constant per session
    bf16* xbf   = (bf16*)ws;                       // BIG mode only
    char* wbase = big ? (ws + WS_XBF_BYTES) : ws;
    bf16*  W1f   = (bf16*)wbase;
    bf16*  W2f   = (bf16*)(wbase + WB_W2F);
    bf16*  W3f   = (bf16*)(wbase + WB_W3F);
    float* cano  = (float*)(wbase + WB_CANO);

    canonicalize<<<483, 256, 0, stream>>>(W1, W2, W3, b1, b2, b3, W4, b4,
                                          W1f, W2f, W3f, cano);
    if (big) convert_x<<<6250, 256, 0, stream>>>(x, xbf);
    fused_mlp<<<E_TOTAL / 64, 256, 0, stream>>>(
        big ? (const void*)xbf : x, ei, ef, W1f, W2f, W3f,
        cano, big ? 0 : -1, out);
}